// Round 1
// baseline (793.010 us; speedup 1.0000x reference)
//
#include <hip/hip_runtime.h>
#include <hip/hip_bf16.h>

// ---------------------------------------------------------------------------
// 2-layer GraphSAGE (mean aggr) on gfx950.
// Pipeline (all on `stream`):
//   memset cnt=0 -> prep weights (Wt = [W_l;W_r]^T in bf16)
//   -> histogram(dst) -> 3-kernel exclusive scan -> CSR scatter
//   -> gather x = bf16(emb[x_idx]) into xA1[:,256:512]
//   -> L1 agg (CSR gather-only, fp32 accum) -> xA1[:,0:256]
//   -> L1 GEMM [100k,512]@[512,256] bf16 MFMA -> x1 bf16 into d_out scratch
//   -> L2 agg -> mean2 bf16 into d_out scratch
//   -> L2 GEMM -> x2 fp32 in-place over scratch rows (BN=256: block owns rows)
//   -> gather drug/se rows from x2.
// d_out x-region rows are 1KB: [mean2(512B bf16) | x1(512B bf16)] before L2
// GEMM, final fp32 x2 row after. ws usage ~110 MB.
// ---------------------------------------------------------------------------

typedef __bf16 bf16x8 __attribute__((ext_vector_type(8)));
typedef __bf16 bf16x4 __attribute__((ext_vector_type(4)));
typedef float  f32x4  __attribute__((ext_vector_type(4)));

#define ROWB 1024  // bytes per A row: 512 bf16 (K = 512 = [mean | x])

__device__ __forceinline__ void async_copy16(void* lds_dst, const void* g_src) {
  // LDS side resolves to wave-uniform base + lane*16 (per-lane ptr is
  // consistent with that: lane l passes base + l*16).
  __builtin_amdgcn_global_load_lds(
      (const __attribute__((address_space(1))) void*)g_src,
      (__attribute__((address_space(3))) void*)lds_dst, 16, 0, 0);
}

// ---- CSR build ------------------------------------------------------------

__global__ void hist_kernel(const int* __restrict__ dst, int* __restrict__ cnt, int E) {
  int e = blockIdx.x * 256 + threadIdx.x;
  if (e < E) atomicAdd(&cnt[dst[e]], 1);
}

__global__ void scan_block_sums(const int* __restrict__ cnt, int* __restrict__ bsum, int n) {
  __shared__ int s[256];
  int i = blockIdx.x * 256 + threadIdx.x;
  s[threadIdx.x] = (i < n) ? cnt[i] : 0;
  __syncthreads();
  for (int d = 128; d > 0; d >>= 1) {
    if (threadIdx.x < d) s[threadIdx.x] += s[threadIdx.x + d];
    __syncthreads();
  }
  if (threadIdx.x == 0) bsum[blockIdx.x] = s[0];
}

__global__ void scan_tops(const int* __restrict__ bsum, int* __restrict__ bbase, int nb) {
  __shared__ int s[512];
  int t = threadIdx.x;
  int v = (t < nb) ? bsum[t] : 0;
  s[t] = v; __syncthreads();
  for (int d = 1; d < 512; d <<= 1) {
    int add = (t >= d) ? s[t - d] : 0;
    __syncthreads();
    s[t] += add;
    __syncthreads();
  }
  if (t < nb) bbase[t] = s[t] - v;  // exclusive
}

__global__ void scan_final(const int* __restrict__ cnt, const int* __restrict__ bbase,
                           int* __restrict__ offs, int n) {
  __shared__ int s[256];
  int t = threadIdx.x, i = blockIdx.x * 256 + t;
  int v = (i < n) ? cnt[i] : 0;
  s[t] = v; __syncthreads();
  for (int d = 1; d < 256; d <<= 1) {
    int add = (t >= d) ? s[t - d] : 0;
    __syncthreads();
    s[t] += add;
    __syncthreads();
  }
  if (i < n) offs[i] = bbase[blockIdx.x] + s[t] - v;  // exclusive start
}

__global__ void scatter_kernel(const int* __restrict__ src, const int* __restrict__ dst,
                               int* __restrict__ offs, int* __restrict__ csr, int E) {
  int e = blockIdx.x * 256 + threadIdx.x;
  if (e < E) {
    int p = atomicAdd(&offs[dst[e]], 1);  // offs ends at segment END
    csr[p] = src[e];
  }
}

// ---- feature prep ---------------------------------------------------------

// Wt[n][k] = bf16( k<256 ? Wl[k][n] : Wr[k-256][n] ), row-major [256][512]
__global__ void prep_w_kernel(const float* __restrict__ W1l, const float* __restrict__ W1r,
                              const float* __restrict__ W2l, const float* __restrict__ W2r,
                              __bf16* __restrict__ Wt1, __bf16* __restrict__ Wt2) {
  int idx = blockIdx.x * 256 + threadIdx.x;  // 0 .. 2*131072-1
  int which = idx >> 17;
  int j = idx & 131071;
  int n = j >> 9, k = j & 511;
  const float* Wl = which ? W2l : W1l;
  const float* Wr = which ? W2r : W1r;
  float v = (k < 256) ? Wl[k * 256 + n] : Wr[(k - 256) * 256 + n];
  (which ? Wt2 : Wt1)[j] = (__bf16)v;
}

// x-half gather: xbase points at (row stride ROWB) destination of the x slot
__global__ void gather_x_kernel(const float* __restrict__ emb, const int* __restrict__ x_idx,
                                char* __restrict__ xbase, int N) {
  int wave = threadIdx.x >> 6, lane = threadIdx.x & 63;
  int i = blockIdx.x * 4 + wave;
  if (i >= N) return;
  int s = x_idx[i];
  float4 v = *(const float4*)(emb + (size_t)s * 256 + lane * 4);
  bf16x4 o = { (__bf16)v.x, (__bf16)v.y, (__bf16)v.z, (__bf16)v.w };
  *(bf16x4*)(xbase + (size_t)i * ROWB + lane * 8) = o;
}

// ---- mean aggregation (gather-only, one wave per node) --------------------

__global__ void sage_agg(const char* __restrict__ srcbase,  // row r: srcbase + r*ROWB, 256 bf16
                         char* __restrict__ dstbase,        // node i: dstbase + i*ROWB, 256 bf16
                         const int* __restrict__ csr, const int* __restrict__ cnt,
                         const int* __restrict__ off_end, int N) {
  int wave = threadIdx.x >> 6, lane = threadIdx.x & 63;
  int i = blockIdx.x * 4 + wave;
  if (i >= N) return;
  int deg = cnt[i];
  int start = off_end[i] - deg;
  const int* lp = csr + start;
  float a0 = 0.f, a1 = 0.f, a2 = 0.f, a3 = 0.f;
  int j = 0;
  for (; j + 1 < deg; j += 2) {  // unroll-2: pipeline the dependent loads
    int s0 = lp[j], s1 = lp[j + 1];
    bf16x4 v0 = *(const bf16x4*)(srcbase + (size_t)s0 * ROWB + lane * 8);
    bf16x4 v1 = *(const bf16x4*)(srcbase + (size_t)s1 * ROWB + lane * 8);
    a0 += (float)v0[0] + (float)v1[0];
    a1 += (float)v0[1] + (float)v1[1];
    a2 += (float)v0[2] + (float)v1[2];
    a3 += (float)v0[3] + (float)v1[3];
  }
  if (j < deg) {
    int s0 = lp[j];
    bf16x4 v0 = *(const bf16x4*)(srcbase + (size_t)s0 * ROWB + lane * 8);
    a0 += (float)v0[0]; a1 += (float)v0[1]; a2 += (float)v0[2]; a3 += (float)v0[3];
  }
  float inv = 1.0f / (float)(deg > 0 ? deg : 1);
  bf16x4 o = { (__bf16)(a0 * inv), (__bf16)(a1 * inv), (__bf16)(a2 * inv), (__bf16)(a3 * inv) };
  *(bf16x4*)(dstbase + (size_t)i * ROWB + lane * 8) = o;
}

// ---- fused GEMM: out[M,256] = A[M,512] @ Wcat[512,256] + bias -------------
// BM=64, BN=256 (full), BK=32, 256 threads = 4 waves, wave tile 32x128.
// LDS fragment-ordered 16B chunks; staged via global_load_lds width=16.
// OUT_F32=0: store bf16 x1 at row*ROWB+512 ; OUT_F32=1: store fp32 row in place.

template <int OUT_F32>
__global__ __launch_bounds__(256) void gemm_sage(const char* __restrict__ Abase,
                                                 const __bf16* __restrict__ Wt,
                                                 const float* __restrict__ bias,
                                                 char* __restrict__ outbase, int M) {
  __shared__ __align__(16) char lds[40960];  // 2 bufs x (A 4KB + B 16KB)
  const int tid = threadIdx.x;
  const int wave = tid >> 6, lane = tid & 63;
  const int r = lane & 15, q = lane >> 4;
  const int wm = wave >> 1, wn = wave & 1;
  const int row0 = blockIdx.x * 64;

  f32x4 acc[2][8];
#pragma unroll
  for (int t = 0; t < 2; ++t)
#pragma unroll
    for (int u = 0; u < 8; ++u) acc[t][u] = (f32x4)0.f;

  auto stage = [&](int kk, int buf) {
    char* lbase = lds + buf * 20480;
    // A: each wave stages one 16-row group; lane l -> chunk (r=l&15, q=l>>4)
    int rowA = row0 + wave * 16 + r;
    rowA = rowA < M ? rowA : M - 1;  // clamp: garbage rows masked at store
    async_copy16(lbase + wave * 1024 + lane * 16,
                 Abase + (size_t)rowA * ROWB + (size_t)(kk * 32 + q * 8) * 2);
    // B: each wave stages 4 of 16 n-groups from Wt [256][512]
#pragma unroll
    for (int i = 0; i < 4; ++i) {
      int h = wave * 4 + i;
      async_copy16(lbase + 4096 + h * 1024 + lane * 16,
                   (const char*)Wt + ((size_t)(h * 16 + r) * 512 + kk * 32 + q * 8) * 2);
    }
  };

  stage(0, 0);
  for (int kk = 0; kk < 16; ++kk) {
    __syncthreads();  // compiler drains vmcnt before s_barrier -> staging done
    if (kk < 15) stage(kk + 1, (kk + 1) & 1);
    const char* lbase = lds + (kk & 1) * 20480;
    bf16x8 a0 = *(const bf16x8*)(lbase + (wm * 2 + 0) * 1024 + lane * 16);
    bf16x8 a1 = *(const bf16x8*)(lbase + (wm * 2 + 1) * 1024 + lane * 16);
#pragma unroll
    for (int u = 0; u < 8; ++u) {
      bf16x8 b = *(const bf16x8*)(lbase + 4096 + (wn * 8 + u) * 1024 + lane * 16);
      acc[0][u] = __builtin_amdgcn_mfma_f32_16x16x32_bf16(a0, b, acc[0][u], 0, 0, 0);
      acc[1][u] = __builtin_amdgcn_mfma_f32_16x16x32_bf16(a1, b, acc[1][u], 0, 0, 0);
    }
  }

  // epilogue. All global A reads drained at the kk=15 barrier, so in-place
  // fp32 overwrite of this block's own rows (sole owner, BN=256) is safe.
#pragma unroll
  for (int t = 0; t < 2; ++t) {
    int rbase = row0 + wm * 32 + t * 16 + q * 4;
#pragma unroll
    for (int u = 0; u < 8; ++u) {
      int col = wn * 128 + u * 16 + r;
      float bv = bias[col];
#pragma unroll
      for (int j = 0; j < 4; ++j) {
        int row = rbase + j;
        if (row < M) {
          float v = acc[t][u][j] + bv;
          if (OUT_F32)
            *(float*)(outbase + (size_t)row * ROWB + col * 4) = v;
          else
            *(__bf16*)(outbase + (size_t)row * ROWB + 512 + col * 2) = (__bf16)v;
        }
      }
    }
  }
}

// ---- final index gathers --------------------------------------------------

__global__ void gather_out_kernel(const float* __restrict__ x2, const int* __restrict__ drug,
                                  const int* __restrict__ se, float* __restrict__ out,
                                  int nd, int ns) {
  int wave = threadIdx.x >> 6, lane = threadIdx.x & 63;
  int ro = blockIdx.x * 4 + wave;
  if (ro >= nd + ns) return;
  int node = (ro < nd) ? drug[ro] : se[ro - nd];
  float4 v = *(const float4*)(x2 + (size_t)node * 256 + lane * 4);
  *(float4*)(out + (size_t)ro * 256 + lane * 4) = v;
}

// ---------------------------------------------------------------------------

extern "C" void kernel_launch(void* const* d_in, const int* in_sizes, int n_in,
                              void* d_out, int out_size, void* d_ws, size_t ws_size,
                              hipStream_t stream) {
  const float* emb  = (const float*)d_in[0];
  const float* W1l  = (const float*)d_in[1];
  const float* b1l  = (const float*)d_in[2];
  const float* W1r  = (const float*)d_in[3];
  const float* W2l  = (const float*)d_in[4];
  const float* b2l  = (const float*)d_in[5];
  const float* W2r  = (const float*)d_in[6];
  const int* x_idx  = (const int*)d_in[7];
  const int* edge   = (const int*)d_in[8];
  const int* drug   = (const int*)d_in[9];
  const int* se     = (const int*)d_in[10];

  const int N = in_sizes[7];       // 100000
  const int E = in_sizes[8] / 2;   // 1600000
  const int nd = in_sizes[9], ns = in_sizes[10];
  const int* esrc = edge;
  const int* edst = edge + E;

  // workspace carve (~110 MB)
  char* ws = (char*)d_ws;
  size_t off = 0;
  char* xA1 = ws;                       off += (size_t)((N + 127) & ~127) * ROWB;
  __bf16* Wt1 = (__bf16*)(ws + off);    off += 512 * 256 * 2;
  __bf16* Wt2 = (__bf16*)(ws + off);    off += 512 * 256 * 2;
  int* cnt  = (int*)(ws + off);         off += ((size_t)N * 4 + 255) & ~(size_t)255;
  int* offs = (int*)(ws + off);         off += ((size_t)N * 4 + 255) & ~(size_t)255;
  int* csr  = (int*)(ws + off);         off += ((size_t)E * 4 + 255) & ~(size_t)255;
  int* bsum = (int*)(ws + off);         off += 4096;
  int* bbase = (int*)(ws + off);        off += 4096;

  // d_out carve: [drug nd*256 | se ns*256 | x2 N*256] fp32
  float* outp = (float*)d_out;
  float* x2 = outp + (size_t)(nd + ns) * 256;
  char* scratch2 = (char*)x2;  // rows of 1KB: [mean2 bf16 | x1 bf16] -> x2 fp32

  const int NB = (N + 255) / 256;        // 391 (<=512 required)
  const int EB = (E + 255) / 256;
  const int QB = (N + 3) / 4;
  const int GB = (N + 63) / 64;

  hipMemsetAsync(cnt, 0, (size_t)N * 4, stream);
  prep_w_kernel<<<(2 * 131072) / 256, 256, 0, stream>>>(W1l, W1r, W2l, W2r, Wt1, Wt2);
  hist_kernel<<<EB, 256, 0, stream>>>(edst, cnt, E);
  scan_block_sums<<<NB, 256, 0, stream>>>(cnt, bsum, N);
  scan_tops<<<1, 512, 0, stream>>>(bsum, bbase, NB);
  scan_final<<<NB, 256, 0, stream>>>(cnt, bbase, offs, N);
  scatter_kernel<<<EB, 256, 0, stream>>>(esrc, edst, offs, csr, E);

  gather_x_kernel<<<QB, 256, 0, stream>>>(emb, x_idx, xA1 + 512, N);
  // layer 1
  sage_agg<<<QB, 256, 0, stream>>>(xA1 + 512, xA1, csr, cnt, offs, N);
  gemm_sage<0><<<GB, 256, 0, stream>>>(xA1, Wt1, b1l, scratch2, N);
  // layer 2
  sage_agg<<<QB, 256, 0, stream>>>(scratch2 + 512, scratch2, csr, cnt, offs, N);
  gemm_sage<1><<<GB, 256, 0, stream>>>(scratch2, Wt2, b2l, scratch2, N);

  gather_out_kernel<<<(nd + ns + 3) / 4, 256, 0, stream>>>(x2, drug, se, outp, nd, ns);
}